// Round 4
// baseline (202.846 us; speedup 1.0000x reference)
//
#include <hip/hip_runtime.h>

#define B_    64
#define HW_   196
#define HWP_  224
#define D_    768
#define E_    256
#define C_    10
#define MP_   (B_*HWP_)   // 14336 padded rows
#define K3K_  (E_*D_)     // 196608 deep-K for final contraction
#define K3NB_ 192         // K-split blocks for k3

typedef _Float16 half8 __attribute__((ext_vector_type(8)));
typedef _Float16 half4 __attribute__((ext_vector_type(4)));
typedef float    f32x4 __attribute__((ext_vector_type(4)));

// ---------------- K0x: fp32 x -> fp16 hi/lo, zero-padded [B][HWP][D] ----------------
__global__ __launch_bounds__(256) void k0_x(const float* __restrict__ x,
                                            _Float16* __restrict__ xhi,
                                            _Float16* __restrict__ xlo) {
  size_t i4 = ((size_t)blockIdx.x * 256 + threadIdx.x) * 4;
  int d  = (int)(i4 % D_);
  size_t row = i4 / D_;
  int hp = (int)(row % HWP_);
  int b  = (int)(row / HWP_);
  float4 v = make_float4(0.f, 0.f, 0.f, 0.f);
  if (hp < HW_) v = *(const float4*)&x[((size_t)b * HW_ + hp) * D_ + d];
  float vv[4] = {v.x, v.y, v.z, v.w};
  half4 h, l;
#pragma unroll
  for (int j = 0; j < 4; j++) {
    _Float16 hj = (_Float16)vv[j];
    float r = vv[j] - (float)hj;
    h[j] = hj;
    l[j] = (_Float16)r;
  }
  *(half4*)&xhi[i4] = h;
  *(half4*)&xlo[i4] = l;
}

// ---------------- K0w: fp32 ag_w -> fp16 hi/lo [E][D] ----------------
__global__ __launch_bounds__(256) void k0_w(const float* __restrict__ w,
                                            _Float16* __restrict__ whi,
                                            _Float16* __restrict__ wlo) {
  size_t i4 = ((size_t)blockIdx.x * 256 + threadIdx.x) * 4;
  float4 v = *(const float4*)&w[i4];
  float vv[4] = {v.x, v.y, v.z, v.w};
  half4 h, l;
#pragma unroll
  for (int j = 0; j < 4; j++) {
    _Float16 hj = (_Float16)vv[j];
    float r = vv[j] - (float)hj;
    h[j] = hj;
    l[j] = (_Float16)r;
  }
  *(half4*)&whi[i4] = h;
  *(half4*)&wlo[i4] = l;
}

// ---------------- K1: sign GEMM, LDS-free — MFMA fragments loaded direct from global ----
// A[m][k] and B[e][k] are both K-contiguous; the 16x16x32 frag (row=lane&15,
// k=(lane>>4)*8+j) is a contiguous 16B/lane load. No LDS, no barriers, no conflicts.
// Wave tile 32x64 (2x4 frags, 3 split terms = 24 MFMA/iter). Block = 4 waves
// stacked in m (all share B frags -> L1 hits). Grid 112x4 = 448 blocks.
__global__ __launch_bounds__(256) void k1_signs(const _Float16* __restrict__ xhi,
                                                const _Float16* __restrict__ xlo,
                                                const _Float16* __restrict__ whi,
                                                const _Float16* __restrict__ wlo,
                                                const float* __restrict__ bias,
                                                _Float16* __restrict__ st) {
  const int tid = threadIdx.x;
  const int wave = tid >> 6, lane = tid & 63;
  const int q = lane >> 4, l15 = lane & 15;
  const int m0 = blockIdx.x * 128 + wave * 32;
  const int n0 = blockIdx.y * 64;
  const _Float16* a0p = &xhi[(size_t)(m0 + l15) * D_];
  const _Float16* a1p = &xhi[(size_t)(m0 + 16 + l15) * D_];
  const _Float16* l0p = &xlo[(size_t)(m0 + l15) * D_];
  const _Float16* l1p = &xlo[(size_t)(m0 + 16 + l15) * D_];
  const _Float16* bhp = &whi[(size_t)(n0 + l15) * D_];
  const _Float16* blp = &wlo[(size_t)(n0 + l15) * D_];
  f32x4 acc[2][4] = {};

#pragma unroll 2
  for (int k0 = 0; k0 < D_; k0 += 32) {
    const int k = k0 + q * 8;
    half8 a0 = *(const half8*)&a0p[k];
    half8 a1 = *(const half8*)&a1p[k];
    half8 l0 = *(const half8*)&l0p[k];
    half8 l1 = *(const half8*)&l1p[k];
    half8 bh[4], bl[4];
#pragma unroll
    for (int nt = 0; nt < 4; nt++) {
      bh[nt] = *(const half8*)&bhp[(size_t)nt * 16 * D_ + k];
      bl[nt] = *(const half8*)&blp[(size_t)nt * 16 * D_ + k];
    }
#pragma unroll
    for (int nt = 0; nt < 4; nt++) {
      acc[0][nt] = __builtin_amdgcn_mfma_f32_16x16x32_f16(a0, bh[nt], acc[0][nt], 0, 0, 0);
      acc[0][nt] = __builtin_amdgcn_mfma_f32_16x16x32_f16(l0, bh[nt], acc[0][nt], 0, 0, 0);
      acc[0][nt] = __builtin_amdgcn_mfma_f32_16x16x32_f16(a0, bl[nt], acc[0][nt], 0, 0, 0);
      acc[1][nt] = __builtin_amdgcn_mfma_f32_16x16x32_f16(a1, bh[nt], acc[1][nt], 0, 0, 0);
      acc[1][nt] = __builtin_amdgcn_mfma_f32_16x16x32_f16(l1, bh[nt], acc[1][nt], 0, 0, 0);
      acc[1][nt] = __builtin_amdgcn_mfma_f32_16x16x32_f16(a1, bl[nt], acc[1][nt], 0, 0, 0);
    }
  }
  // epilogue: +bias, sign, transposed store ST[b][e][hp] (pads hp>=196 get 0)
#pragma unroll
  for (int mt = 0; mt < 2; mt++)
#pragma unroll
    for (int nt = 0; nt < 4; nt++) {
      int e = n0 + nt * 16 + l15;
      float bv = bias[e];
#pragma unroll
      for (int r = 0; r < 4; r++) {
        int m = m0 + mt * 16 + q * 4 + r;   // C/D: row=quad*4+reg, col=lane&15
        int b = m / HWP_;
        int hp = m - b * HWP_;
        float v = acc[mt][nt][r] + bv;
        _Float16 s = (hp < HW_ && v > 0.0f) ? (_Float16)1.0f : (_Float16)0.0f;
        st[((size_t)b * E_ + e) * HWP_ + hp] = s;
      }
    }
}

// ---------------- K2: per-batch G = S^T · X  (M=256 e, N=768 d, K=224 hp) ----------------
__global__ __launch_bounds__(256) void k2_g(const _Float16* __restrict__ st,
                                            const _Float16* __restrict__ xhi,
                                            _Float16* __restrict__ g) {
  __shared__ _Float16 As[128 * 40];
  __shared__ _Float16 Bs[128 * 40];   // Bs[d][k] (transposed during staging)
  const int b  = blockIdx.y;
  const int e0 = (blockIdx.x / 6) * 128;
  const int d0 = (blockIdx.x % 6) * 128;
  const int tid = threadIdx.x;
  const int wave = tid >> 6, lane = tid & 63;
  const int wm = (wave & 1) * 64, wn = (wave >> 1) * 64;
  const int q = lane >> 4, l15 = lane & 15;
  const int sr = tid >> 2, sk = (tid & 3) * 8;
  const int kk = tid >> 3, dc0 = (tid & 7) * 16;
  f32x4 acc[4][4] = {};

  for (int k0 = 0; k0 < HWP_; k0 += 32) {
    __syncthreads();
#pragma unroll
    for (int rr = 0; rr < 128; rr += 64) {
      int r = sr + rr;
      *(half8*)&As[r * 40 + sk] =
          *(const half8*)&st[((size_t)b * E_ + e0 + r) * HWP_ + k0 + sk];
    }
    {
      const _Float16* src = &xhi[((size_t)b * HWP_ + k0 + kk) * D_ + d0 + dc0];
      half8 t0 = *(const half8*)&src[0];
      half8 t1 = *(const half8*)&src[8];
#pragma unroll
      for (int j = 0; j < 8; j++) {
        Bs[(dc0 + j) * 40 + kk]     = t0[j];
        Bs[(dc0 + 8 + j) * 40 + kk] = t1[j];
      }
    }
    __syncthreads();
    half8 af[4], bfr[4];
#pragma unroll
    for (int t = 0; t < 4; t++) {
      af[t]  = *(const half8*)&As[(wm + t * 16 + l15) * 40 + q * 8];
      bfr[t] = *(const half8*)&Bs[(wn + t * 16 + l15) * 40 + q * 8];
    }
#pragma unroll
    for (int mt = 0; mt < 4; mt++)
#pragma unroll
      for (int nt = 0; nt < 4; nt++)
        acc[mt][nt] = __builtin_amdgcn_mfma_f32_16x16x32_f16(af[mt], bfr[nt], acc[mt][nt], 0, 0, 0);
  }
#pragma unroll
  for (int mt = 0; mt < 4; mt++)
#pragma unroll
    for (int nt = 0; nt < 4; nt++) {
      int d = d0 + wn + nt * 16 + l15;
#pragma unroll
      for (int r = 0; r < 4; r++) {
        int e = e0 + wm + mt * 16 + q * 4 + r;
        g[((size_t)b * E_ + e) * D_ + d] = (_Float16)acc[mt][nt][r];
      }
    }
}

// ---------------- K2b: permute lm_w -> W2[c][e*768+d] fp16, c padded to 16 ----------------
__global__ __launch_bounds__(192) void k2b_w2(const float* __restrict__ lmw,
                                              _Float16* __restrict__ w2) {
  const int e = blockIdx.x, c = blockIdx.y, t = threadIdx.x;
  _Float16* dst = &w2[(size_t)c * K3K_ + (size_t)e * D_ + t * 4];
  half4 o;
  if (c < C_) {
    float4 v = *(const float4*)&lmw[((size_t)e * C_ + c) * D_ + t * 4];
    o[0] = (_Float16)v.x; o[1] = (_Float16)v.y; o[2] = (_Float16)v.z; o[3] = (_Float16)v.w;
  } else {
    o[0] = o[1] = o[2] = o[3] = (_Float16)0.0f;
  }
  *(half4*)dst = o;
}

// ---------------- K3: preds = G_flat(64 x 196608) · W2^T, deep-K split MFMA ----------------
__global__ __launch_bounds__(256) void k3_mfma(const _Float16* __restrict__ g,
                                               const _Float16* __restrict__ w2,
                                               float* __restrict__ out) {
  __shared__ float sp[B_ * C_];
  const int tid = threadIdx.x;
  const int wave = tid >> 6, lane = tid & 63;
  const int q = lane >> 4, l15 = lane & 15;
  const int kbase = blockIdx.x * (K3K_ / K3NB_) + wave * 256;
  f32x4 acc[4] = {};

  for (int i = tid; i < B_ * C_; i += 256) sp[i] = 0.0f;

#pragma unroll
  for (int ks = 0; ks < 8; ks++) {
    int k = kbase + ks * 32 + q * 8;
    half8 bfrag = *(const half8*)&w2[(size_t)l15 * K3K_ + k];
#pragma unroll
    for (int mt = 0; mt < 4; mt++) {
      half8 afrag = *(const half8*)&g[(size_t)(mt * 16 + l15) * K3K_ + k];
      acc[mt] = __builtin_amdgcn_mfma_f32_16x16x32_f16(afrag, bfrag, acc[mt], 0, 0, 0);
    }
  }
  __syncthreads();
  int c = l15;
  if (c < C_) {
#pragma unroll
    for (int mt = 0; mt < 4; mt++)
#pragma unroll
      for (int r = 0; r < 4; r++) {
        int b = mt * 16 + q * 4 + r;
        atomicAdd(&sp[b * C_ + c], acc[mt][r]);
      }
  }
  __syncthreads();
  const float scale = 1.0f / (196.0f * 256.0f);
  for (int i = tid; i < B_ * C_; i += 256) atomicAdd(&out[i], sp[i] * scale);
}

extern "C" void kernel_launch(void* const* d_in, const int* in_sizes, int n_in,
                              void* d_out, int out_size, void* d_ws, size_t ws_size,
                              hipStream_t stream) {
  const float* x    = (const float*)d_in[0];   // (64,196,768)
  const float* ag_w = (const float*)d_in[1];   // (256,768)
  const float* ag_b = (const float*)d_in[2];   // (256,)
  const float* lm_w = (const float*)d_in[3];   // (2560,768)
  float* out = (float*)d_out;                  // (64,10)

  char* ws = (char*)d_ws;
  const size_t XP_BYTES = (size_t)B_ * HWP_ * D_ * 2;   // 22,020,096
  const size_t W_BYTES  = (size_t)E_ * D_ * 2;          //    393,216
  const size_t ST_BYTES = (size_t)B_ * E_ * HWP_ * 2;   //  7,340,032
  const size_t G_BYTES  = (size_t)B_ * E_ * D_ * 2;     // 25,165,824
  _Float16* xhi = (_Float16*)(ws);
  _Float16* xlo = (_Float16*)(ws + XP_BYTES);
  _Float16* whi = (_Float16*)(ws + 2 * XP_BYTES);
  _Float16* wlo = (_Float16*)(ws + 2 * XP_BYTES + W_BYTES);
  _Float16* st  = (_Float16*)(ws + 2 * XP_BYTES + 2 * W_BYTES);
  _Float16* gb  = (_Float16*)(ws + 2 * XP_BYTES + 2 * W_BYTES + ST_BYTES);
  _Float16* w2  = (_Float16*)(ws + 2 * XP_BYTES + 2 * W_BYTES + ST_BYTES + G_BYTES);
  // total ws use: ~83 MB

  hipMemsetAsync(d_out, 0, (size_t)out_size * sizeof(float), stream);

  k0_x<<<dim3((B_ * HWP_ * D_) / 4 / 256), dim3(256), 0, stream>>>(x, xhi, xlo);
  k0_w<<<dim3((E_ * D_) / 4 / 256), dim3(256), 0, stream>>>(ag_w, whi, wlo);
  k2b_w2<<<dim3(E_, 16), dim3(192), 0, stream>>>(lm_w, w2);
  k1_signs<<<dim3(MP_ / 128, E_ / 64), dim3(256), 0, stream>>>(xhi, xlo, whi, wlo, ag_b, st);
  k2_g<<<dim3((E_ / 128) * (D_ / 128), B_), dim3(256), 0, stream>>>(st, xhi, gb);
  k3_mfma<<<dim3(K3NB_), dim3(256), 0, stream>>>(gb, w2, out);
}

// Round 5
// 174.958 us; speedup vs baseline: 1.1594x; 1.1594x over previous
//
#include <hip/hip_runtime.h>

#define B_    64
#define HW_   196
#define HWP_  224
#define D_    768
#define E_    256
#define C_    10
#define MP_   (B_*HWP_)   // 14336 padded rows
#define K3K_  (E_*D_)     // 196608 deep-K for final contraction
#define K3NB_ 192         // K-split blocks for k3

typedef _Float16 half8 __attribute__((ext_vector_type(8)));
typedef _Float16 half4 __attribute__((ext_vector_type(4)));
typedef float    f32x4 __attribute__((ext_vector_type(4)));

// ---- K0x: fp32 x -> fp16 hi/lo (padded [B][HWP][D]) + transposed xt [B][D][HWP] ----
// 64hp x 64d tile per block; LDS-tiled transpose kills k2's per-block scalar transpose.
__global__ __launch_bounds__(256) void k0_x(const float* __restrict__ x,
                                            _Float16* __restrict__ xhi,
                                            _Float16* __restrict__ xlo,
                                            _Float16* __restrict__ xt) {
  __shared__ _Float16 th[64 * 68];   // stride 68: 4-way max on transpose reads (1.58x, ok)
  const int bid = blockIdx.x;
  const int b = bid / 48, rem = bid % 48;
  const int hpt = rem / 12, dt = rem % 12;
  int hp0 = hpt * 64; if (hpt == 3) hp0 = 160;   // tiles {0,64,128,160}: overlap is idempotent
  const int d0 = dt * 64;
  const int t = threadIdx.x;
  const int lr = t >> 4;          // 0..15
  const int dc = (t & 15) * 4;    // 0..60
#pragma unroll
  for (int rr = 0; rr < 4; rr++) {
    int row = rr * 16 + lr;       // hp_local
    int hp = hp0 + row;
    float4 v = make_float4(0.f, 0.f, 0.f, 0.f);
    if (hp < HW_) v = *(const float4*)&x[((size_t)b * HW_ + hp) * D_ + d0 + dc];
    float vv[4] = {v.x, v.y, v.z, v.w};
    half4 h, l;
#pragma unroll
    for (int j = 0; j < 4; j++) {
      _Float16 hj = (_Float16)vv[j];
      h[j] = hj;
      l[j] = (_Float16)(vv[j] - (float)hj);
    }
    size_t o = ((size_t)b * HWP_ + hp) * D_ + d0 + dc;
    *(half4*)&xhi[o] = h;
    *(half4*)&xlo[o] = l;
    *(half4*)&th[row * 68 + dc] = h;
  }
  __syncthreads();
#pragma unroll
  for (int rr = 0; rr < 4; rr++) {
    int dl = rr * 16 + lr;        // d_local
    half4 o;
#pragma unroll
    for (int j = 0; j < 4; j++) o[j] = th[(dc + j) * 68 + dl];
    *(half4*)&xt[((size_t)b * D_ + d0 + dl) * HWP_ + hp0 + dc] = o;
  }
}

// ---------------- K0w: fp32 ag_w -> fp16 hi/lo [E][D] ----------------
__global__ __launch_bounds__(256) void k0_w(const float* __restrict__ w,
                                            _Float16* __restrict__ whi,
                                            _Float16* __restrict__ wlo) {
  size_t i4 = ((size_t)blockIdx.x * 256 + threadIdx.x) * 4;
  float4 v = *(const float4*)&w[i4];
  float vv[4] = {v.x, v.y, v.z, v.w};
  half4 h, l;
#pragma unroll
  for (int j = 0; j < 4; j++) {
    _Float16 hj = (_Float16)vv[j];
    h[j] = hj;
    l[j] = (_Float16)(vv[j] - (float)hj);
  }
  *(half4*)&whi[i4] = h;
  *(half4*)&wlo[i4] = l;
}

// ---------------- K1: sign GEMM, 3-term split-fp16 MFMA ----------------
// Block tile 128m x 64n -> grid 112x4 = 448 blocks (R2's 224 left CUs idle).
// 4 waves 2x2, wave-tile 64x32: 24 MFMA : 12 ds_read_b128 per iter.
__global__ __launch_bounds__(256) void k1_signs(const _Float16* __restrict__ xhi,
                                                const _Float16* __restrict__ xlo,
                                                const _Float16* __restrict__ whi,
                                                const _Float16* __restrict__ wlo,
                                                const float* __restrict__ bias,
                                                _Float16* __restrict__ st) {
  __shared__ _Float16 Ah[128 * 40];   // stride 40: proven low-conflict (R2: 2.75M cy)
  __shared__ _Float16 Al[128 * 40];
  __shared__ _Float16 Bh[64 * 40];
  __shared__ _Float16 Bl[64 * 40];
  const int m0 = blockIdx.x * 128;
  const int n0 = blockIdx.y * 64;
  const int tid = threadIdx.x;
  const int wave = tid >> 6, lane = tid & 63;
  const int wm = (wave & 1) * 64, wn = (wave >> 1) * 32;
  const int q = lane >> 4, l15 = lane & 15;
  const int sr = tid >> 2;          // 0..63
  const int sk = (tid & 3) * 8;
  f32x4 acc[4][2] = {};

  for (int k0 = 0; k0 < D_; k0 += 32) {
    __syncthreads();
    *(half8*)&Ah[sr * 40 + sk]        = *(const half8*)&xhi[(size_t)(m0 + sr) * D_ + k0 + sk];
    *(half8*)&Ah[(sr + 64) * 40 + sk] = *(const half8*)&xhi[(size_t)(m0 + 64 + sr) * D_ + k0 + sk];
    *(half8*)&Al[sr * 40 + sk]        = *(const half8*)&xlo[(size_t)(m0 + sr) * D_ + k0 + sk];
    *(half8*)&Al[(sr + 64) * 40 + sk] = *(const half8*)&xlo[(size_t)(m0 + 64 + sr) * D_ + k0 + sk];
    *(half8*)&Bh[sr * 40 + sk]        = *(const half8*)&whi[(size_t)(n0 + sr) * D_ + k0 + sk];
    *(half8*)&Bl[sr * 40 + sk]        = *(const half8*)&wlo[(size_t)(n0 + sr) * D_ + k0 + sk];
    __syncthreads();
    half8 af[4], alf[4], bfh[2], bfl[2];
#pragma unroll
    for (int t = 0; t < 4; t++) {
      af[t]  = *(const half8*)&Ah[(wm + t * 16 + l15) * 40 + q * 8];
      alf[t] = *(const half8*)&Al[(wm + t * 16 + l15) * 40 + q * 8];
    }
#pragma unroll
    for (int t = 0; t < 2; t++) {
      bfh[t] = *(const half8*)&Bh[(wn + t * 16 + l15) * 40 + q * 8];
      bfl[t] = *(const half8*)&Bl[(wn + t * 16 + l15) * 40 + q * 8];
    }
#pragma unroll
    for (int mt = 0; mt < 4; mt++)
#pragma unroll
      for (int nt = 0; nt < 2; nt++) {
        acc[mt][nt] = __builtin_amdgcn_mfma_f32_16x16x32_f16(af[mt],  bfh[nt], acc[mt][nt], 0, 0, 0);
        acc[mt][nt] = __builtin_amdgcn_mfma_f32_16x16x32_f16(alf[mt], bfh[nt], acc[mt][nt], 0, 0, 0);
        acc[mt][nt] = __builtin_amdgcn_mfma_f32_16x16x32_f16(af[mt],  bfl[nt], acc[mt][nt], 0, 0, 0);
      }
  }
#pragma unroll
  for (int mt = 0; mt < 4; mt++)
#pragma unroll
    for (int nt = 0; nt < 2; nt++) {
      int e = n0 + wn + nt * 16 + l15;
      float bv = bias[e];
#pragma unroll
      for (int r = 0; r < 4; r++) {
        int m = m0 + wm + mt * 16 + q * 4 + r;   // C/D: row=quad*4+reg, col=lane&15
        int b = m / HWP_;
        int hp = m - b * HWP_;
        float v = acc[mt][nt][r] + bv;
        _Float16 s = (hp < HW_ && v > 0.0f) ? (_Float16)1.0f : (_Float16)0.0f;
        st[((size_t)b * E_ + e) * HWP_ + hp] = s;
      }
    }
}

// ---------------- K2: per-batch G = S^T · X, both operands row-major in K=hp ----------
// A = st[b][e][hp], B = xt[b][d][hp]. 128e x 128d tile, K=224, grid 12x64.
__global__ __launch_bounds__(256) void k2_g(const _Float16* __restrict__ st,
                                            const _Float16* __restrict__ xt,
                                            _Float16* __restrict__ g) {
  __shared__ _Float16 As[128 * 40];
  __shared__ _Float16 Bs[128 * 40];
  const int b  = blockIdx.y;
  const int e0 = (blockIdx.x / 6) * 128;
  const int d0 = (blockIdx.x % 6) * 128;
  const int tid = threadIdx.x;
  const int wave = tid >> 6, lane = tid & 63;
  const int wm = (wave & 1) * 64, wn = (wave >> 1) * 64;
  const int q = lane >> 4, l15 = lane & 15;
  const int sr = tid >> 2, sk = (tid & 3) * 8;
  f32x4 acc[4][4] = {};

  const _Float16* arow = &st[((size_t)b * E_ + e0) * HWP_];
  const _Float16* brow = &xt[((size_t)b * D_ + d0) * HWP_];

  for (int k0 = 0; k0 < HWP_; k0 += 32) {
    __syncthreads();
    *(half8*)&As[sr * 40 + sk]        = *(const half8*)&arow[(size_t)sr * HWP_ + k0 + sk];
    *(half8*)&As[(sr + 64) * 40 + sk] = *(const half8*)&arow[(size_t)(sr + 64) * HWP_ + k0 + sk];
    *(half8*)&Bs[sr * 40 + sk]        = *(const half8*)&brow[(size_t)sr * HWP_ + k0 + sk];
    *(half8*)&Bs[(sr + 64) * 40 + sk] = *(const half8*)&brow[(size_t)(sr + 64) * HWP_ + k0 + sk];
    __syncthreads();
    half8 af[4], bfr[4];
#pragma unroll
    for (int t = 0; t < 4; t++) {
      af[t]  = *(const half8*)&As[(wm + t * 16 + l15) * 40 + q * 8];
      bfr[t] = *(const half8*)&Bs[(wn + t * 16 + l15) * 40 + q * 8];
    }
#pragma unroll
    for (int mt = 0; mt < 4; mt++)
#pragma unroll
      for (int nt = 0; nt < 4; nt++)
        acc[mt][nt] = __builtin_amdgcn_mfma_f32_16x16x32_f16(af[mt], bfr[nt], acc[mt][nt], 0, 0, 0);
  }
#pragma unroll
  for (int mt = 0; mt < 4; mt++)
#pragma unroll
    for (int nt = 0; nt < 4; nt++) {
      int d = d0 + wn + nt * 16 + l15;
#pragma unroll
      for (int r = 0; r < 4; r++) {
        int e = e0 + wm + mt * 16 + q * 4 + r;
        g[((size_t)b * E_ + e) * D_ + d] = (_Float16)acc[mt][nt][r];
      }
    }
}

// ---------------- K2b: permute lm_w -> W2[c][e*768+d] fp16, c padded to 16 ----------------
__global__ __launch_bounds__(192) void k2b_w2(const float* __restrict__ lmw,
                                              _Float16* __restrict__ w2) {
  const int e = blockIdx.x, c = blockIdx.y, t = threadIdx.x;
  _Float16* dst = &w2[(size_t)c * K3K_ + (size_t)e * D_ + t * 4];
  half4 o;
  if (c < C_) {
    float4 v = *(const float4*)&lmw[((size_t)e * C_ + c) * D_ + t * 4];
    o[0] = (_Float16)v.x; o[1] = (_Float16)v.y; o[2] = (_Float16)v.z; o[3] = (_Float16)v.w;
  } else {
    o[0] = o[1] = o[2] = o[3] = (_Float16)0.0f;
  }
  *(half4*)dst = o;
}

// ---------------- K3: preds = G_flat(64 x 196608) · W2^T, deep-K split MFMA ----------------
__global__ __launch_bounds__(256) void k3_mfma(const _Float16* __restrict__ g,
                                               const _Float16* __restrict__ w2,
                                               float* __restrict__ out) {
  __shared__ float sp[B_ * C_];
  const int tid = threadIdx.x;
  const int wave = tid >> 6, lane = tid & 63;
  const int q = lane >> 4, l15 = lane & 15;
  const int kbase = blockIdx.x * (K3K_ / K3NB_) + wave * 256;
  f32x4 acc[4] = {};

  for (int i = tid; i < B_ * C_; i += 256) sp[i] = 0.0f;

#pragma unroll
  for (int ks = 0; ks < 8; ks++) {
    int k = kbase + ks * 32 + q * 8;
    half8 bfrag = *(const half8*)&w2[(size_t)l15 * K3K_ + k];
#pragma unroll
    for (int mt = 0; mt < 4; mt++) {
      half8 afrag = *(const half8*)&g[(size_t)(mt * 16 + l15) * K3K_ + k];
      acc[mt] = __builtin_amdgcn_mfma_f32_16x16x32_f16(afrag, bfrag, acc[mt], 0, 0, 0);
    }
  }
  __syncthreads();
  int c = l15;
  if (c < C_) {
#pragma unroll
    for (int mt = 0; mt < 4; mt++)
#pragma unroll
      for (int r = 0; r < 4; r++) {
        int b = mt * 16 + q * 4 + r;
        atomicAdd(&sp[b * C_ + c], acc[mt][r]);
      }
  }
  __syncthreads();
  const float scale = 1.0f / (196.0f * 256.0f);
  for (int i = tid; i < B_ * C_; i += 256) atomicAdd(&out[i], sp[i] * scale);
}

extern "C" void kernel_launch(void* const* d_in, const int* in_sizes, int n_in,
                              void* d_out, int out_size, void* d_ws, size_t ws_size,
                              hipStream_t stream) {
  const float* x    = (const float*)d_in[0];   // (64,196,768)
  const float* ag_w = (const float*)d_in[1];   // (256,768)
  const float* ag_b = (const float*)d_in[2];   // (256,)
  const float* lm_w = (const float*)d_in[3];   // (2560,768)
  float* out = (float*)d_out;                  // (64,10)

  char* ws = (char*)d_ws;
  // layout (bytes): xhi | xt | whi | wlo | st | w2 | xlo (g aliases xlo's slot, xlo dead after k1)
  _Float16* xhi = (_Float16*)(ws + 0);
  _Float16* xt  = (_Float16*)(ws + 22020096);
  _Float16* whi = (_Float16*)(ws + 44040192);
  _Float16* wlo = (_Float16*)(ws + 44433408);
  _Float16* st  = (_Float16*)(ws + 44826624);
  _Float16* w2  = (_Float16*)(ws + 52166656);
  _Float16* xlo = (_Float16*)(ws + 58458112);
  _Float16* gb  = (_Float16*)(ws + 58458112);   // 25.2 MB, extends to ~83.6 MB total

  hipMemsetAsync(d_out, 0, (size_t)out_size * sizeof(float), stream);

  k0_x<<<dim3(B_ * 4 * 12), dim3(256), 0, stream>>>(x, xhi, xlo, xt);
  k0_w<<<dim3((E_ * D_) / 4 / 256), dim3(256), 0, stream>>>(ag_w, whi, wlo);
  k2b_w2<<<dim3(E_, 16), dim3(192), 0, stream>>>(lm_w, w2);
  k1_signs<<<dim3(MP_ / 128, E_ / 64), dim3(256), 0, stream>>>(xhi, xlo, whi, wlo, ag_b, st);
  k2_g<<<dim3(12, B_), dim3(256), 0, stream>>>(st, xt, gb);
  k3_mfma<<<dim3(K3NB_), dim3(256), 0, stream>>>(gb, w2, out);
}